// Round 11
// baseline (1280.053 us; speedup 1.0000x reference)
//
#include <hip/hip_runtime.h>
#include <math.h>

// Problem constants: B=1024, N=200, E=128, fp32.
constexpr int Bc = 1024;
constexpr int Nc = 200;
constexpr int Ec = 128;

// R11: ticket-fused softmax. Ledger: R5/R8/R10 identical to 0.4us across
// three different MLP structures -> per-wave MLP conclusively not the
// limiter; all-nt dist is pinned at ~58-60us (3.5 TB/s streaming
// equilibrium). Remaining lever: the separate softmax kernel (~5-6us +
// dispatch gap). Fold it into dist via the rocPRIM-style last-block ticket:
// after a block writes its 40 rows of xs/os, __threadfence + atomicAdd on a
// per-batch counter; the 5th arriver re-reads the batch's 200 entries
// (L2-hot) and does the softmax inline -- overlapped with other batches'
// streaming instead of serialized after ALL of it. Side benefit: fused
// dispatch (~63-66us) rises above the 61us fill wall -> rocprof visibility
// returns. Cost: 4KB hipMemsetAsync to zero tickets (graph-capturable).
constexpr int ROWS    = 5;                 // rows per 32-lane group
constexpr int GROUPS  = 8;                 // 256 threads / 32
constexpr int NSPLIT  = 5;                 // blocks per batch (5*40 = 200 rows)

typedef float v4f __attribute__((ext_vector_type(4)));

__global__ __launch_bounds__(256, 4) void fused_dist_softmax(
    const float* __restrict__ q,      // (B,E)
    const float* __restrict__ q_p,    // (B,E)
    const float* __restrict__ m,      // (B,N,E)
    const float* __restrict__ m_c,    // (B,N,E)
    const float* __restrict__ A1,     // (E)
    const float* __restrict__ A2,     // (E)
    const float* __restrict__ biases, // (B,N)
    const float* __restrict__ mask,   // (B,N)
    int*  __restrict__ cnt,           // (B) arrival tickets (zeroed per launch)
    float* __restrict__ xs_ws,        // (B,N) softmax arguments -> workspace
    float* __restrict__ out)          // (B,N) final output
{
    const int j    = blockIdx.x;     // 0..NSPLIT-1  (which 40-row slice)
    const int b    = blockIdx.y;     // batch
    const int tid  = threadIdx.x;
    const int hw   = tid >> 5;       // group id 0..7
    const int lane = tid & 31;
    const int e0   = lane * 4;

    const int n0 = j * (GROUPS * ROWS) + hw * ROWS;

    // Per-lane chunks of q, q_p, A1, A2 (small, hot in cache).
    const v4f qv  = *reinterpret_cast<const v4f*>(q   + (size_t)b * Ec + e0);
    const v4f qpv = *reinterpret_cast<const v4f*>(q_p + (size_t)b * Ec + e0);
    const v4f a1v = *reinterpret_cast<const v4f*>(A1  + e0);
    const v4f a2v = *reinterpret_cast<const v4f*>(A2  + e0);

    const float* mb  = m   + (size_t)b * Nc * Ec;
    const float* mcb = m_c + (size_t)b * Nc * Ec;

    // 10 nt loads (proven best cache policy: single-use stream, no L3 thrash).
    v4f mv[ROWS], mcv[ROWS];
#pragma unroll
    for (int r = 0; r < ROWS; ++r) {
        mv[r]  = __builtin_nontemporal_load(
                     reinterpret_cast<const v4f*>(mb  + (size_t)(n0 + r) * Ec + e0));
        mcv[r] = __builtin_nontemporal_load(
                     reinterpret_cast<const v4f*>(mcb + (size_t)(n0 + r) * Ec + e0));
    }
    asm volatile("" : "+v"(mv[0]), "+v"(mv[1]), "+v"(mv[2]), "+v"(mv[3]), "+v"(mv[4]),
                      "+v"(mcv[0]), "+v"(mcv[1]), "+v"(mcv[2]), "+v"(mcv[3]), "+v"(mcv[4]));

    float s_att[ROWS], s_out[ROWS];
#pragma unroll
    for (int r = 0; r < ROWS; ++r) {
        float sa = 0.f, so = 0.f;
#pragma unroll
        for (int c = 0; c < 4; ++c) {
            float t1 = (qv[c]  - mv[r][c])  * a1v[c];  sa = fmaf(t1, t1, sa);
            float t2 = (qpv[c] - mv[r][c])  * a2v[c];  sa = fmaf(t2, t2, sa);
            float u1 = (qv[c]  - mcv[r][c]) * a1v[c];  so = fmaf(u1, u1, so);
            float u2 = (qpv[c] - mcv[r][c]) * a2v[c];  so = fmaf(u2, u2, so);
        }
        s_att[r] = sa;
        s_out[r] = so;
    }

    // 10 interleaved shuffle-reduce chains (xor <=16 stays in the 32-lane half).
#pragma unroll
    for (int off = 16; off > 0; off >>= 1) {
#pragma unroll
        for (int r = 0; r < ROWS; ++r) {
            s_att[r] += __shfl_xor(s_att[r], off);
            s_out[r] += __shfl_xor(s_out[r], off);
        }
    }

    if (lane == 0) {
#pragma unroll
        for (int r = 0; r < ROWS; ++r) {
            const int n = n0 + r;
            const float bb = biases[(size_t)b * Nc + n];
            const float mk = mask[(size_t)b * Nc + n];
            // att_dist = d1 + bias + d2 + bias = s_att + 2*bias
            xs_ws[(size_t)b * Nc + n] = -(s_att[r] + 2.f * bb) * mk;
            out  [(size_t)b * Nc + n] =  (s_out[r] + 2.f * bb) * mk;
        }
    }

    // ---- last-block ticket: 5th arriver for batch b does the softmax ----
    __shared__ int lastflag;
    __shared__ float red_s[8];  // 4 max + 4 sum
    __threadfence();            // release our xs/os writes device-wide
    if (tid == 0) {
        const int old = atomicAdd(&cnt[b], 1);   // device-scope
        lastflag = (old == NSPLIT - 1);
    }
    __syncthreads();
    if (!lastflag) return;
    __threadfence();            // acquire: see all 5 blocks' xs/os writes

    const float x  = (tid < Nc) ? xs_ws[(size_t)b * Nc + tid] : -INFINITY;
    const float os = (tid < Nc) ? out  [(size_t)b * Nc + tid] : 0.f;

    // max
    float wmax = x;
#pragma unroll
    for (int off = 32; off > 0; off >>= 1)
        wmax = fmaxf(wmax, __shfl_xor(wmax, off));
    if ((tid & 63) == 0) red_s[tid >> 6] = wmax;
    __syncthreads();
    const float gmax = fmaxf(fmaxf(red_s[0], red_s[1]), fmaxf(red_s[2], red_s[3]));

    // sum of exp
    const float ex = (tid < Nc) ? expf(x - gmax) : 0.f;
    float wsum = ex;
#pragma unroll
    for (int off = 32; off > 0; off >>= 1)
        wsum += __shfl_xor(wsum, off);
    if ((tid & 63) == 0) red_s[4 + (tid >> 6)] = wsum;
    __syncthreads();
    const float gsum = (red_s[4] + red_s[5]) + (red_s[6] + red_s[7]);

    if (tid < Nc) {
        out[(size_t)b * Nc + tid] = os * (ex / gsum);
    }
}

extern "C" void kernel_launch(void* const* d_in, const int* in_sizes, int n_in,
                              void* d_out, int out_size, void* d_ws, size_t ws_size,
                              hipStream_t stream) {
    const float* q      = (const float*)d_in[0];
    const float* q_p    = (const float*)d_in[1];
    const float* m      = (const float*)d_in[2];
    const float* m_c    = (const float*)d_in[3];
    const float* A1     = (const float*)d_in[4];
    const float* A2     = (const float*)d_in[5];
    const float* biases = (const float*)d_in[6];
    const float* mask   = (const float*)d_in[7];
    float* out = (float*)d_out;

    // Workspace layout: [0,4KB) = tickets (B ints), [4KB, 4KB+800KB) = xs_ws.
    int*   cnt   = (int*)d_ws;
    float* xs_ws = (float*)((char*)d_ws + 4096);

    hipMemsetAsync(cnt, 0, Bc * sizeof(int), stream);   // graph-capturable

    dim3 grid(NSPLIT, Bc, 1);
    fused_dist_softmax<<<grid, 256, 0, stream>>>(q, q_p, m, m_c, A1, A2,
                                                 biases, mask, cnt, xs_ws, out);
}

// Round 12
// 220.485 us; speedup vs baseline: 5.8056x; 5.8056x over previous
//
#include <hip/hip_runtime.h>
#include <math.h>

// Problem constants: B=1024, N=200, E=128, fp32.
constexpr int Bc = 1024;
constexpr int Nc = 200;
constexpr int Ec = 128;

// R12: revert R11 (ticket fusion = 1.2ms: __threadfence on gfx950 is an L2
// writeback for cross-XCD visibility; 5120 blocks x 2 fences serialized).
// Back to the proven R5/R8 two-kernel structure (221.3us best) with ONE
// delta: de-interleave the load burst. R5/R8 issued m,mc,m,mc per row
// (512B alternating between regions ~100MB apart); now all 5 m-rows
// (2.5KB contiguous) then all 5 mc-rows. Tests the last source-level
// stream-shape hypothesis; if null, the 3.5 TB/s nt equilibrium is
// DRAM-side and we are at the practical roofline.
constexpr int ROWS    = 5;                 // rows per 32-lane group
constexpr int GROUPS  = 8;                 // 256 threads / 32
constexpr int NSPLIT  = 5;                 // blocks per batch (5*40 = 200 rows)

typedef float v4f __attribute__((ext_vector_type(4)));

__global__ __launch_bounds__(256, 4) void dist_phase(
    const float* __restrict__ q,      // (B,E)
    const float* __restrict__ q_p,    // (B,E)
    const float* __restrict__ m,      // (B,N,E)
    const float* __restrict__ m_c,    // (B,N,E)
    const float* __restrict__ A1,     // (E)
    const float* __restrict__ A2,     // (E)
    const float* __restrict__ biases, // (B,N)
    const float* __restrict__ mask,   // (B,N)
    float* __restrict__ xs_ws,        // (B,N) softmax arguments -> workspace
    float* __restrict__ out)          // (B,N) out_dist*mask (scaled later by k2)
{
    const int j    = blockIdx.x;     // 0..NSPLIT-1  (which 40-row slice)
    const int b    = blockIdx.y;     // batch
    const int tid  = threadIdx.x;
    const int hw   = tid >> 5;       // group id 0..7
    const int lane = tid & 31;
    const int e0   = lane * 4;

    const int n0 = j * (GROUPS * ROWS) + hw * ROWS;

    // Per-lane chunks of q, q_p, A1, A2 (small, hot in cache).
    const v4f qv  = *reinterpret_cast<const v4f*>(q   + (size_t)b * Ec + e0);
    const v4f qpv = *reinterpret_cast<const v4f*>(q_p + (size_t)b * Ec + e0);
    const v4f a1v = *reinterpret_cast<const v4f*>(A1  + e0);
    const v4f a2v = *reinterpret_cast<const v4f*>(A2  + e0);

    const float* mb  = m   + (size_t)b * Nc * Ec;
    const float* mcb = m_c + (size_t)b * Nc * Ec;

    // nt loads (proven best cache policy), de-interleaved: all m rows first
    // (2.5KB contiguous run per lane-group), then all m_c rows.
    v4f mv[ROWS], mcv[ROWS];
#pragma unroll
    for (int r = 0; r < ROWS; ++r) {
        mv[r]  = __builtin_nontemporal_load(
                     reinterpret_cast<const v4f*>(mb  + (size_t)(n0 + r) * Ec + e0));
    }
#pragma unroll
    for (int r = 0; r < ROWS; ++r) {
        mcv[r] = __builtin_nontemporal_load(
                     reinterpret_cast<const v4f*>(mcb + (size_t)(n0 + r) * Ec + e0));
    }
    asm volatile("" : "+v"(mv[0]), "+v"(mv[1]), "+v"(mv[2]), "+v"(mv[3]), "+v"(mv[4]),
                      "+v"(mcv[0]), "+v"(mcv[1]), "+v"(mcv[2]), "+v"(mcv[3]), "+v"(mcv[4]));

    float s_att[ROWS], s_out[ROWS];
#pragma unroll
    for (int r = 0; r < ROWS; ++r) {
        float sa = 0.f, so = 0.f;
#pragma unroll
        for (int c = 0; c < 4; ++c) {
            float t1 = (qv[c]  - mv[r][c])  * a1v[c];  sa = fmaf(t1, t1, sa);
            float t2 = (qpv[c] - mv[r][c])  * a2v[c];  sa = fmaf(t2, t2, sa);
            float u1 = (qv[c]  - mcv[r][c]) * a1v[c];  so = fmaf(u1, u1, so);
            float u2 = (qpv[c] - mcv[r][c]) * a2v[c];  so = fmaf(u2, u2, so);
        }
        s_att[r] = sa;
        s_out[r] = so;
    }

    // 10 interleaved shuffle-reduce chains (xor <=16 stays in the 32-lane half).
#pragma unroll
    for (int off = 16; off > 0; off >>= 1) {
#pragma unroll
        for (int r = 0; r < ROWS; ++r) {
            s_att[r] += __shfl_xor(s_att[r], off);
            s_out[r] += __shfl_xor(s_out[r], off);
        }
    }

    if (lane == 0) {
#pragma unroll
        for (int r = 0; r < ROWS; ++r) {
            const int n = n0 + r;
            const float bb = biases[(size_t)b * Nc + n];
            const float mk = mask[(size_t)b * Nc + n];
            // att_dist = d1 + bias + d2 + bias = s_att + 2*bias
            xs_ws[(size_t)b * Nc + n] = -(s_att[r] + 2.f * bb) * mk;
            out  [(size_t)b * Nc + n] =  (s_out[r] + 2.f * bb) * mk;
        }
    }
}

// One 256-thread block per batch: softmax over the 200 entries, scale os.
__global__ __launch_bounds__(256, 4) void softmax_phase(
    const float* __restrict__ xs_ws,  // (B,N)
    float* __restrict__ out)          // (B,N) in: os, out: os * softmax
{
    const int b   = blockIdx.x;
    const int tid = threadIdx.x;

    __shared__ float red_s[8];  // 4 max + 4 sum

    const float x  = (tid < Nc) ? xs_ws[(size_t)b * Nc + tid] : -INFINITY;
    const float os = (tid < Nc) ? out  [(size_t)b * Nc + tid] : 0.f;

    // max
    float wmax = x;
#pragma unroll
    for (int off = 32; off > 0; off >>= 1)
        wmax = fmaxf(wmax, __shfl_xor(wmax, off));
    if ((tid & 63) == 0) red_s[tid >> 6] = wmax;
    __syncthreads();
    const float gmax = fmaxf(fmaxf(red_s[0], red_s[1]), fmaxf(red_s[2], red_s[3]));

    // sum of exp
    const float ex = (tid < Nc) ? expf(x - gmax) : 0.f;
    float wsum = ex;
#pragma unroll
    for (int off = 32; off > 0; off >>= 1)
        wsum += __shfl_xor(wsum, off);
    if ((tid & 63) == 0) red_s[4 + (tid >> 6)] = wsum;
    __syncthreads();
    const float gsum = (red_s[4] + red_s[5]) + (red_s[6] + red_s[7]);

    if (tid < Nc) {
        out[(size_t)b * Nc + tid] = os * (ex / gsum);
    }
}

extern "C" void kernel_launch(void* const* d_in, const int* in_sizes, int n_in,
                              void* d_out, int out_size, void* d_ws, size_t ws_size,
                              hipStream_t stream) {
    const float* q      = (const float*)d_in[0];
    const float* q_p    = (const float*)d_in[1];
    const float* m      = (const float*)d_in[2];
    const float* m_c    = (const float*)d_in[3];
    const float* A1     = (const float*)d_in[4];
    const float* A2     = (const float*)d_in[5];
    const float* biases = (const float*)d_in[6];
    const float* mask   = (const float*)d_in[7];
    float* out   = (float*)d_out;
    float* xs_ws = (float*)d_ws;     // needs B*N*4 = 800 KB of workspace

    dim3 grid1(NSPLIT, Bc, 1);
    dist_phase<<<grid1, 256, 0, stream>>>(q, q_p, m, m_c, A1, A2, biases, mask,
                                          xs_ws, out);
    softmax_phase<<<Bc, 256, 0, stream>>>(xs_ws, out);
}